// Round 14
// baseline (133.220 us; speedup 1.0000x reference)
//
#include <hip/hip_runtime.h>

// ---------------- types & helpers (NO inline asm) ----------------
using short8 = __attribute__((ext_vector_type(8))) short;   // 8 x bf16 (4 VGPRs)
using f32x4  = __attribute__((ext_vector_type(4))) float;
using u16x4  = __attribute__((ext_vector_type(4))) unsigned short;

#define MFMA16(A,B,C) __builtin_amdgcn_mfma_f32_16x16x32_bf16((A),(B),(C),0,0,0)

#if __has_builtin(__builtin_amdgcn_exp2f)
#define EXP2(x) __builtin_amdgcn_exp2f(x)
#else
#define EXP2(x) exp2f(x)
#endif

__device__ __forceinline__ unsigned short f2b(float f) {
  unsigned u = __float_as_uint(f);
  return (unsigned short)((u + 0x7fffu + ((u >> 16) & 1u)) >> 16);  // RNE
}
__device__ __forceinline__ short8 mk8(unsigned a, unsigned b, unsigned c, unsigned d) {
  union { unsigned u[4]; short8 s; } t; t.u[0]=a; t.u[1]=b; t.u[2]=c; t.u[3]=d; return t.s;
}
// trunc-pack two f32 -> bf16x2 (1 VALU op; r12-proven with self-consistent ls)
__device__ __forceinline__ unsigned pk2(float lo, float hi) {
  return __builtin_amdgcn_perm(__float_as_uint(hi), __float_as_uint(lo), 0x07060302u);
}
// 8 consecutive f32 -> bf16x8 fragment (optional scale, RNE)
__device__ __forceinline__ short8 w8s(const float* p, float s) {
  const f32x4* q = (const f32x4*)p;
  f32x4 a = q[0], b = q[1];
  short8 r;
  r[0]=(short)f2b(a[0]*s); r[1]=(short)f2b(a[1]*s); r[2]=(short)f2b(a[2]*s); r[3]=(short)f2b(a[3]*s);
  r[4]=(short)f2b(b[0]*s); r[5]=(short)f2b(b[1]*s); r[6]=(short)f2b(b[2]*s); r[7]=(short)f2b(b[3]*s);
  return r;
}

// T=512, N=128, D=64, H=4, HID=OUT=64

// ---------------- kernel 1: xin = x + pe, transpose to [n][t][d] bf16 (r13-exact) ----------------
__global__ void prep_kernel(const float* __restrict__ x, const float* __restrict__ pe,
                            unsigned* __restrict__ xinT) {
  int i2 = blockIdx.x * 256 + threadIdx.x;
  const float2* xp = (const float2*)x;
  const float2* pp = (const float2*)pe;
  float2 a = xp[i2], b = pp[i2];
  float s0 = a.x + b.x, s1 = a.y + b.y;
  int i = i2 << 1;
  int t = i >> 13, rem = i & 8191, n = rem >> 6, d = rem & 63;
  unsigned v = (unsigned)f2b(s0) | ((unsigned)f2b(s1) << 16);
  xinT[((n * 512 + t) * 64 + d) >> 1] = v;
}

// ---------------- attn building blocks ----------------
// Q projection for 16 rows at qb16 (r11-proven; scratch = 2 KiB swizzled carve)
__device__ __forceinline__ void qproj16(
    const unsigned short* xn, const short8 (&wqB)[4][2], unsigned short* sQw,
    int qb16, int lg, int lm, short8 (&qB)[2]) {
  const f32x4 zero4 = {0.f, 0.f, 0.f, 0.f};
  short8 aX0 = *(const short8*)(xn + (qb16 + lm) * 64 + lg * 8);
  short8 aX1 = *(const short8*)(xn + (qb16 + lm) * 64 + 32 + lg * 8);
#pragma unroll
  for (int nt = 0; nt < 4; ++nt) {
    f32x4 acc = zero4;
    acc = MFMA16(aX0, wqB[nt][0], acc);
    acc = MFMA16(aX1, wqB[nt][1], acc);
#pragma unroll
    for (int r = 0; r < 4; ++r) {
      int qr = lg * 4 + r;
      int e  = nt * 16 + lm;
      sQw[qr * 64 + (e ^ ((qr & 7) << 3))] = f2b(acc[r]);
    }
  }
#pragma unroll
  for (int ks = 0; ks < 2; ++ks)
    qB[ks] = *(const short8*)&sQw[lm * 64 + ((ks * 32 + lg * 8) ^ ((lm & 7) << 3))];
}

// stage K (swizzled) + V (kappa2 fragments) for phase half p; wave w stages 32 rows
__device__ __forceinline__ void stage_half(
    const unsigned short* xn, int p, int w, int lg, int lm, int l,
    const float* bk, const float* bv, unsigned short* sK, short8* sVf) {
  const f32x4 zero4 = {0.f, 0.f, 0.f, 0.f};
  int s0g = p * 256 + w * 32;          // global row base
  int sl0 = w * 32;                    // phase-local row base
  short8 aX[2][2];
#pragma unroll
  for (int km = 0; km < 2; ++km) {
    aX[km][0] = *(const short8*)(xn + (s0g + km * 16 + lm) * 64 + lg * 8);
    aX[km][1] = *(const short8*)(xn + (s0g + km * 16 + lm) * 64 + 32 + lg * 8);
  }
#pragma unroll
  for (int nt = 0; nt < 4; ++nt) {
    // per-nt scoped weight fragments (caps register pressure)
    const float* bko = bk + (nt * 16 + lm) * 64 + lg * 8;
    const float* bvo = bv + (nt * 16 + lm) * 64 + lg * 8;
    short8 wk0 = w8s(bko, 1.0f), wk1 = w8s(bko + 32, 1.0f);
    short8 wv0 = w8s(bvo, 1.0f), wv1 = w8s(bvo + 32, 1.0f);
    f32x4 k0 = zero4, k1 = zero4, v0 = zero4, v1 = zero4;
    k0 = MFMA16(aX[0][0], wk0, k0); k0 = MFMA16(aX[0][1], wk1, k0);
    k1 = MFMA16(aX[1][0], wk0, k1); k1 = MFMA16(aX[1][1], wk1, k1);
    v0 = MFMA16(aX[0][0], wv0, v0); v0 = MFMA16(aX[0][1], wv1, v0);
    v1 = MFMA16(aX[1][0], wv0, v1); v1 = MFMA16(aX[1][1], wv1, v1);
#pragma unroll
    for (int r = 0; r < 4; ++r) {
      int row0 = sl0 + lg * 4 + r;
      int row1 = sl0 + 16 + lg * 4 + r;
      int e    = nt * 16 + lm;
      sK[row0 * 64 + (e ^ ((row0 & 7) << 3))] = f2b(k0[r]);
      sK[row1 * 64 + (e ^ ((row1 & 7) << 3))] = f2b(k1[r]);
    }
    short8 vv;
    vv[0]=(short)f2b(v0[0]); vv[1]=(short)f2b(v0[1]);
    vv[2]=(short)f2b(v0[2]); vv[3]=(short)f2b(v0[3]);
    vv[4]=(short)f2b(v1[0]); vv[5]=(short)f2b(v1[1]);
    vv[6]=(short)f2b(v1[2]); vv[7]=(short)f2b(v1[3]);
    sVf[(w * 4 + nt) * 64 + l] = vv;
  }
}

// slabs [kb_lo, kb_hi] for a 16-row chunk at qb16 (phase-local base pbase).
// O^T accumulation: oAcc[ot] = MFMA(vB-as-A, pA-as-B, .) -> lane (lg,lm) holds
// O[q=lm][o=ot*16+4lg+r]; ls = MFMA(ones-as-A, pA-as-B) -> ls[q=lm] in all regs.
// (A/B fragments share the same lane->element mapping, and vB/pA use the same
//  kappa2, so the swap needs zero repacking.)
__device__ __forceinline__ void run_chunk(
    const unsigned short* sK, const short8* sVf, const short8 (&qB)[2],
    f32x4 (&oAcc)[4], f32x4& lsAcc, const short8 ones,
    int qb16, int kb_lo, int kb_hi, int pbase, int lg, int lm, int l) {
  const f32x4 zero4 = {0.f, 0.f, 0.f, 0.f};
  for (int kb = kb_lo; kb <= kb_hi; kb += 32) {
    int kl = kb - pbase;
    short8 vB[4];
#pragma unroll
    for (int ot = 0; ot < 4; ++ot) vB[ot] = sVf[(((kl >> 5) * 4) + ot) * 64 + l];
    short8 aK[2][2];
#pragma unroll
    for (int km = 0; km < 2; ++km)
#pragma unroll
      for (int ks = 0; ks < 2; ++ks) {
        int row = kl + km * 16 + lm;
        aK[km][ks] = *(const short8*)&sK[row * 64 + ((ks * 32 + lg * 8) ^ ((row & 7) << 3))];
      }
    f32x4 st[2];
#pragma unroll
    for (int km = 0; km < 2; ++km) {
      f32x4 a = zero4;
      a = MFMA16(aK[km][0], qB[0], a);
      a = MFMA16(aK[km][1], qB[1], a);
      st[km] = a;
    }
    if (kb + 32 > qb16) {               // diagonal-crossing slab
      int qrl = qb16 - kb + lm;
#pragma unroll
      for (int km = 0; km < 2; ++km)
#pragma unroll
        for (int r = 0; r < 4; ++r)
          if (km * 16 + lg * 4 + r > qrl) st[km][r] = -1e30f;
    }
#pragma unroll
    for (int km = 0; km < 2; ++km)
#pragma unroll
      for (int r = 0; r < 4; ++r) st[km][r] = EXP2(st[km][r]);
    short8 pA = mk8(pk2(st[0][0], st[0][1]), pk2(st[0][2], st[0][3]),
                    pk2(st[1][0], st[1][1]), pk2(st[1][2], st[1][3]));
    lsAcc = MFMA16(ones, pA, lsAcc);    // O^T form: ls[q=lm] in every reg
#pragma unroll
    for (int ot = 0; ot < 4; ++ot) oAcc[ot] = MFMA16(vB[ot], pA, oAcc[ot]);
  }
}

// normalize + DIRECT global store: lane (lg,lm) owns row t=qb16+lm,
// features ot*16 + 4lg + r (contiguous u16x4 per ot)
__device__ __forceinline__ void store_chunk(
    const f32x4 (&oAcc)[4], const f32x4& lsAcc, unsigned short* heads,
    int qb16, int n, int h, int lg, int lm) {
  float li = 1.0f / lsAcc[0];           // all 4 regs hold ls[q=lm]
  unsigned short* base = heads + ((qb16 + lm) * 128 + n) * 256 + h * 64 + lg * 4;
#pragma unroll
  for (int ot = 0; ot < 4; ++ot) {
    u16x4 v;
#pragma unroll
    for (int r = 0; r < 4; ++r) v[r] = f2b(oAcc[ot][r] * li);
    *(u16x4*)(base + ot * 16) = v;
  }
}

// ---------------- kernel 2: fused QKV + causal flash attention ----------------
// 512 thr / 8 waves, LDS = 32K sK-half + 32K sVf-half = 65536 B -> 2 blocks/CU
// -> 4 waves/SIMD; grid 512 = ONE co-resident round.
// 16-row chunks, 4/wave {w, 8+w, 23-w, 31-w} = exactly 34 slab-steps/wave.
__global__ __launch_bounds__(512) void attn_kernel(
    const unsigned short* __restrict__ xinT,
    const float* __restrict__ wq, const float* __restrict__ wk,
    const float* __restrict__ wv, unsigned short* __restrict__ heads) {
  __shared__ unsigned short sK[256 * 64];   // 32 KiB, XOR-swizzled (phase half)
  __shared__ short8 sVf[8 * 4 * 64];        // 32 KiB kappa2 V fragments (phase half)

  const int hn = blockIdx.x;
  const int h  = hn & 3;
  const int n  = hn >> 2;
  const int w  = threadIdx.x >> 6;    // 0..7
  const int l  = threadIdx.x & 63;
  const int lg = l >> 4;
  const int lm = l & 15;

  const unsigned short* xn = xinT + n * (512 * 64);
  const f32x4 zero4 = {0.f, 0.f, 0.f, 0.f};
  const float SC = 0.18033688011112042f;   // (1/sqrt(64)) * log2(e)
  const short8 ones = mk8(0x3F803F80u, 0x3F803F80u, 0x3F803F80u, 0x3F803F80u);

  const int qbA = w * 16;           // low half  (0..112)
  const int qbC = (8 + w) * 16;     // low half  (128..240)
  const int qbD = (23 - w) * 16;    // high half (256..368)
  const int qbB = (31 - w) * 16;    // high half (384..496)

  // ---- phase -1: Q projection for all 4 chunks (scratch carved from sK) ----
  short8 qBA[2], qBC[2], qBD[2], qBB[2];
  {
    short8 wqB[4][2];
    const float* bq = wq + h * 64 * 64;
#pragma unroll
    for (int nt = 0; nt < 4; ++nt)
#pragma unroll
      for (int ks = 0; ks < 2; ++ks)
        wqB[nt][ks] = w8s(bq + (nt * 16 + lm) * 64 + ks * 32 + lg * 8, SC);
    unsigned short* sQw = sK + w * 1024;   // 2 KiB per wave
    qproj16(xn, wqB, sQw, qbA, lg, lm, qBA);
    qproj16(xn, wqB, sQw, qbC, lg, lm, qBC);
    qproj16(xn, wqB, sQw, qbD, lg, lm, qBD);
    qproj16(xn, wqB, sQw, qbB, lg, lm, qBB);
  }
  __syncthreads();

  const float* bk = wk + h * 64 * 64;
  const float* bv = wv + h * 64 * 64;

  // ---- phase 0: stage K/V rows [0,256) ----
  stage_half(xn, 0, w, lg, lm, l, bk, bv, sK, sVf);
  __syncthreads();

  // A and C complete entirely in phase 0 (stores don't touch LDS -> no race)
  {
    f32x4 o[4] = {zero4, zero4, zero4, zero4};
    f32x4 ls = zero4;
    run_chunk(sK, sVf, qBA, o, ls, ones, qbA, 0, (qbA >> 5) << 5, 0, lg, lm, l);
    store_chunk(o, ls, heads, qbA, n, h, lg, lm);
  }
  {
    f32x4 o[4] = {zero4, zero4, zero4, zero4};
    f32x4 ls = zero4;
    run_chunk(sK, sVf, qBC, o, ls, ones, qbC, 0, (qbC >> 5) << 5, 0, lg, lm, l);
    store_chunk(o, ls, heads, qbC, n, h, lg, lm);
  }
  // D and B: phase-0 partial (slabs 0..7, no diagonal), state carried
  f32x4 oD[4] = {zero4, zero4, zero4, zero4};
  f32x4 oB[4] = {zero4, zero4, zero4, zero4};
  f32x4 lsD = zero4, lsB = zero4;
  run_chunk(sK, sVf, qBD, oD, lsD, ones, qbD, 0, 224, 0, lg, lm, l);
  run_chunk(sK, sVf, qBB, oB, lsB, ones, qbB, 0, 224, 0, lg, lm, l);

  __syncthreads();   // all waves done with half 0

  // ---- phase 1: stage K/V rows [256,512) ----
  stage_half(xn, 1, w, lg, lm, l, bk, bv, sK, sVf);
  __syncthreads();

  run_chunk(sK, sVf, qBD, oD, lsD, ones, qbD, 256, (qbD >> 5) << 5, 256, lg, lm, l);
  store_chunk(oD, lsD, heads, qbD, n, h, lg, lm);
  run_chunk(sK, sVf, qBB, oB, lsB, ones, qbB, 256, (qbB >> 5) << 5, 256, lg, lm, l);
  store_chunk(oB, lsB, heads, qbB, n, h, lg, lm);
}

// ---------------- kernel 3: out = heads[65536,256] @ wo^T (r13-exact) ----------------
__global__ __launch_bounds__(256) void outproj_kernel(
    const unsigned short* __restrict__ heads,
    const float* __restrict__ wo,
    float* __restrict__ out) {
  const int w  = threadIdx.x >> 6;
  const int l  = threadIdx.x & 63;
  const int lg = l >> 4, lm = l & 15;
  const f32x4 zero4 = {0.f, 0.f, 0.f, 0.f};

  short8 woB[4][8];
#pragma unroll
  for (int nt = 0; nt < 4; ++nt)
#pragma unroll
    for (int ks = 0; ks < 8; ++ks)
      woB[nt][ks] = w8s(wo + (nt * 16 + lm) * 256 + ks * 32 + lg * 8, 1.0f);

  const int wid = blockIdx.x * 4 + w;
  for (int it = 0; it < 2; ++it) {
    int r0 = (wid * 2 + it) * 16;
    f32x4 acc[4];
#pragma unroll
    for (int nt = 0; nt < 4; ++nt) acc[nt] = zero4;
#pragma unroll
    for (int ks = 0; ks < 8; ++ks) {
      short8 aF = *(const short8*)&heads[(r0 + lm) * 256 + ks * 32 + lg * 8];
#pragma unroll
      for (int nt = 0; nt < 4; ++nt)
        acc[nt] = MFMA16(aF, woB[nt][ks], acc[nt]);
    }
#pragma unroll
    for (int nt = 0; nt < 4; ++nt)
#pragma unroll
      for (int r = 0; r < 4; ++r)
        out[(r0 + lg * 4 + r) * 64 + nt * 16 + lm] = acc[nt][r];
  }
}

// ---------------- launch (r13-exact ws layout) ----------------
extern "C" void kernel_launch(void* const* d_in, const int* in_sizes, int n_in,
                              void* d_out, int out_size, void* d_ws, size_t ws_size,
                              hipStream_t stream) {
  const float* x  = (const float*)d_in[0];
  const float* pe = (const float*)d_in[1];
  const float* wq = (const float*)d_in[2];
  const float* wk = (const float*)d_in[3];
  const float* wv = (const float*)d_in[4];
  const float* wo = (const float*)d_in[5];

  unsigned short* xinT  = (unsigned short*)d_ws;                          // 8 MiB  [n][t][d]
  unsigned short* heads = (unsigned short*)((char*)d_ws + (16u << 20));   // 32 MiB [t][n][256]

  prep_kernel<<<8192, 256, 0, stream>>>(x, pe, (unsigned*)xinT);
  attn_kernel<<<512, 512, 0, stream>>>(xinT, wq, wk, wv, heads);
  outproj_kernel<<<512, 256, 0, stream>>>(heads, wo, (float*)d_out);
}

// Round 15
// 111.609 us; speedup vs baseline: 1.1936x; 1.1936x over previous
//
#include <hip/hip_runtime.h>

// ---------------- types & helpers (NO inline asm) ----------------
using short8 = __attribute__((ext_vector_type(8))) short;   // 8 x bf16 (4 VGPRs)
using f32x4  = __attribute__((ext_vector_type(4))) float;
using u16x4  = __attribute__((ext_vector_type(4))) unsigned short;

#define MFMA16(A,B,C) __builtin_amdgcn_mfma_f32_16x16x32_bf16((A),(B),(C),0,0,0)

#if __has_builtin(__builtin_amdgcn_exp2f)
#define EXP2(x) __builtin_amdgcn_exp2f(x)
#else
#define EXP2(x) exp2f(x)
#endif

__device__ __forceinline__ unsigned short f2b(float f) {
  unsigned u = __float_as_uint(f);
  return (unsigned short)((u + 0x7fffu + ((u >> 16) & 1u)) >> 16);  // RNE
}
__device__ __forceinline__ short8 mk8(unsigned a, unsigned b, unsigned c, unsigned d) {
  union { unsigned u[4]; short8 s; } t; t.u[0]=a; t.u[1]=b; t.u[2]=c; t.u[3]=d; return t.s;
}
__device__ __forceinline__ short8 cat8(u16x4 lo, u16x4 hi) {
  union { u16x4 h[2]; short8 s; } t; t.h[0]=lo; t.h[1]=hi; return t.s;
}
// trunc-pack two f32 -> bf16x2 (1 VALU op; r12-proven with self-consistent ls)
__device__ __forceinline__ unsigned pk2(float lo, float hi) {
  return __builtin_amdgcn_perm(__float_as_uint(hi), __float_as_uint(lo), 0x07060302u);
}
// 8 consecutive f32 -> bf16x8 fragment (optional scale, RNE)
__device__ __forceinline__ short8 w8s(const float* p, float s) {
  const f32x4* q = (const f32x4*)p;
  f32x4 a = q[0], b = q[1];
  short8 r;
  r[0]=(short)f2b(a[0]*s); r[1]=(short)f2b(a[1]*s); r[2]=(short)f2b(a[2]*s); r[3]=(short)f2b(a[3]*s);
  r[4]=(short)f2b(b[0]*s); r[5]=(short)f2b(b[1]*s); r[6]=(short)f2b(b[2]*s); r[7]=(short)f2b(b[3]*s);
  return r;
}

// T=512, N=128, D=64, H=4, HID=OUT=64

// ---------------- kernel 1: xin = x + pe, transpose to [n][t][d] bf16 (r14-exact) ----------------
__global__ void prep_kernel(const float* __restrict__ x, const float* __restrict__ pe,
                            unsigned* __restrict__ xinT) {
  int i2 = blockIdx.x * 256 + threadIdx.x;
  const float2* xp = (const float2*)x;
  const float2* pp = (const float2*)pe;
  float2 a = xp[i2], b = pp[i2];
  float s0 = a.x + b.x, s1 = a.y + b.y;
  int i = i2 << 1;
  int t = i >> 13, rem = i & 8191, n = rem >> 6, d = rem & 63;
  unsigned v = (unsigned)f2b(s0) | ((unsigned)f2b(s1) << 16);
  xinT[((n * 512 + t) * 64 + d) >> 1] = v;
}

// ---------------- attn building blocks ----------------
// LDS-free Q^T projection: qt = MFMA(wq-as-A, xin-as-B) -> lane (lg,lm) holds
// Q^T[e=nt*16+4lg+r][q=lm]. Pack qB as B-fragment with kappa'(lg,i) =
// 32ks + 16*(i>>2) + 4lg + (i&3). Bit-identical Q values to the LDS path.
__device__ __forceinline__ void qprojT(
    const unsigned short* xn, const float* bq, float sc, int qb16,
    int lg, int lm, short8 (&qB)[2]) {
  const f32x4 zero4 = {0.f, 0.f, 0.f, 0.f};
  short8 aX0 = *(const short8*)(xn + (qb16 + lm) * 64 + lg * 8);
  short8 aX1 = *(const short8*)(xn + (qb16 + lm) * 64 + 32 + lg * 8);
  f32x4 qt[4];
#pragma unroll
  for (int nt = 0; nt < 4; ++nt) {   // per-nt wq fragments (caps pressure)
    const float* p = bq + (nt * 16 + lm) * 64 + lg * 8;
    short8 w0 = w8s(p, sc), w1 = w8s(p + 32, sc);
    f32x4 a = zero4;
    a = MFMA16(w0, aX0, a);
    a = MFMA16(w1, aX1, a);
    qt[nt] = a;
  }
#pragma unroll
  for (int ks = 0; ks < 2; ++ks) {
    short8 q;
#pragma unroll
    for (int i = 0; i < 8; ++i) q[i] = (short)f2b(qt[2 * ks + (i >> 2)][i & 3]);
    qB[ks] = q;
  }
}

// stage K (swizzled) + V (kappa2 fragments) for phase half p (r14-exact)
__device__ __forceinline__ void stage_half(
    const unsigned short* xn, int p, int w, int lg, int lm, int l,
    const float* bk, const float* bv, unsigned short* sK, short8* sVf) {
  const f32x4 zero4 = {0.f, 0.f, 0.f, 0.f};
  int s0g = p * 256 + w * 32;
  int sl0 = w * 32;
  short8 aX[2][2];
#pragma unroll
  for (int km = 0; km < 2; ++km) {
    aX[km][0] = *(const short8*)(xn + (s0g + km * 16 + lm) * 64 + lg * 8);
    aX[km][1] = *(const short8*)(xn + (s0g + km * 16 + lm) * 64 + 32 + lg * 8);
  }
#pragma unroll
  for (int nt = 0; nt < 4; ++nt) {
    const float* bko = bk + (nt * 16 + lm) * 64 + lg * 8;
    const float* bvo = bv + (nt * 16 + lm) * 64 + lg * 8;
    short8 wk0 = w8s(bko, 1.0f), wk1 = w8s(bko + 32, 1.0f);
    short8 wv0 = w8s(bvo, 1.0f), wv1 = w8s(bvo + 32, 1.0f);
    f32x4 k0 = zero4, k1 = zero4, v0 = zero4, v1 = zero4;
    k0 = MFMA16(aX[0][0], wk0, k0); k0 = MFMA16(aX[0][1], wk1, k0);
    k1 = MFMA16(aX[1][0], wk0, k1); k1 = MFMA16(aX[1][1], wk1, k1);
    v0 = MFMA16(aX[0][0], wv0, v0); v0 = MFMA16(aX[0][1], wv1, v0);
    v1 = MFMA16(aX[1][0], wv0, v1); v1 = MFMA16(aX[1][1], wv1, v1);
#pragma unroll
    for (int r = 0; r < 4; ++r) {
      int row0 = sl0 + lg * 4 + r;
      int row1 = sl0 + 16 + lg * 4 + r;
      int e    = nt * 16 + lm;
      sK[row0 * 64 + (e ^ ((row0 & 7) << 3))] = f2b(k0[r]);
      sK[row1 * 64 + (e ^ ((row1 & 7) << 3))] = f2b(k1[r]);
    }
    short8 vv;
    vv[0]=(short)f2b(v0[0]); vv[1]=(short)f2b(v0[1]);
    vv[2]=(short)f2b(v0[2]); vv[3]=(short)f2b(v0[3]);
    vv[4]=(short)f2b(v1[0]); vv[5]=(short)f2b(v1[1]);
    vv[6]=(short)f2b(v1[2]); vv[7]=(short)f2b(v1[3]);
    sVf[(w * 4 + nt) * 64 + l] = vv;
  }
}

// slabs [kb_lo, kb_hi] for a 16-row chunk at qb16. aK loaded with kappa'
// (two 8B u16x4 per fragment; 4-aligned chunks commute with the XOR swizzle).
// O^T accumulation (r14-proven): lane (lg,lm) -> O[q=lm][o=ot*16+4lg+r].
__device__ __forceinline__ void run_chunk(
    const unsigned short* sK, const short8* sVf, const short8 (&qB)[2],
    f32x4 (&oAcc)[4], f32x4& lsAcc, const short8 ones,
    int qb16, int kb_lo, int kb_hi, int pbase, int lg, int lm, int l) {
  const f32x4 zero4 = {0.f, 0.f, 0.f, 0.f};
  for (int kb = kb_lo; kb <= kb_hi; kb += 32) {
    int kl = kb - pbase;
    short8 vB[4];
#pragma unroll
    for (int ot = 0; ot < 4; ++ot) vB[ot] = sVf[(((kl >> 5) * 4) + ot) * 64 + l];
    f32x4 st[2];
#pragma unroll
    for (int km = 0; km < 2; ++km) {   // per-km aK (8 regs live, not 16)
      int row = kl + km * 16 + lm;
      int rb = row * 64, xorv = (row & 7) << 3;
      u16x4 l00 = *(const u16x4*)&sK[rb + ((4 * lg) ^ xorv)];
      u16x4 l01 = *(const u16x4*)&sK[rb + ((16 + 4 * lg) ^ xorv)];
      u16x4 l10 = *(const u16x4*)&sK[rb + ((32 + 4 * lg) ^ xorv)];
      u16x4 l11 = *(const u16x4*)&sK[rb + ((48 + 4 * lg) ^ xorv)];
      f32x4 a = zero4;
      a = MFMA16(cat8(l00, l01), qB[0], a);
      a = MFMA16(cat8(l10, l11), qB[1], a);
      st[km] = a;
    }
    if (kb + 32 > qb16) {               // diagonal-crossing slab
      int qrl = qb16 - kb + lm;
#pragma unroll
      for (int km = 0; km < 2; ++km)
#pragma unroll
        for (int r = 0; r < 4; ++r)
          if (km * 16 + lg * 4 + r > qrl) st[km][r] = -1e30f;
    }
#pragma unroll
    for (int km = 0; km < 2; ++km)
#pragma unroll
      for (int r = 0; r < 4; ++r) st[km][r] = EXP2(st[km][r]);
    short8 pA = mk8(pk2(st[0][0], st[0][1]), pk2(st[0][2], st[0][3]),
                    pk2(st[1][0], st[1][1]), pk2(st[1][2], st[1][3]));
    lsAcc = MFMA16(ones, pA, lsAcc);    // O^T form: ls[q=lm] in every reg
#pragma unroll
    for (int ot = 0; ot < 4; ++ot) oAcc[ot] = MFMA16(vB[ot], pA, oAcc[ot]);
  }
}

// normalize + DIRECT global store (r14-proven): lane (lg,lm) owns row t=qb16+lm
__device__ __forceinline__ void store_chunk(
    const f32x4 (&oAcc)[4], const f32x4& lsAcc, unsigned short* heads,
    int qb16, int n, int h, int lg, int lm) {
  float li = 1.0f / lsAcc[0];
  unsigned short* base = heads + ((qb16 + lm) * 128 + n) * 256 + h * 64 + lg * 4;
#pragma unroll
  for (int ot = 0; ot < 4; ++ot) {
    u16x4 v;
#pragma unroll
    for (int r = 0; r < 4; ++r) v[r] = f2b(oAcc[ot][r] * li);
    *(u16x4*)(base + ot * 16) = v;
  }
}

// ---------------- kernel 2: fused QKV + causal flash attention ----------------
// 512 thr / 8 waves, LDS = 65536 B -> 2 blocks/CU -> 4 waves/SIMD, grid 512 =
// one co-resident round. 16-row chunks {w, 8+w, 23-w, 31-w} = 34 slab-steps/wave.
// vs r14 (which spilled ~160 MB at the 128-reg cap): Q-proj is LDS-free
// just-in-time (operand-swap), qBD/qBB re-projected in phase 1, only
// oD/oB/lsD/lsB (40 regs) carried across the barrier.
__global__ __launch_bounds__(512) void attn_kernel(
    const unsigned short* __restrict__ xinT,
    const float* __restrict__ wq, const float* __restrict__ wk,
    const float* __restrict__ wv, unsigned short* __restrict__ heads) {
  __shared__ unsigned short sK[256 * 64];   // 32 KiB, XOR-swizzled (phase half)
  __shared__ short8 sVf[8 * 4 * 64];        // 32 KiB kappa2 V fragments (phase half)

  const int hn = blockIdx.x;
  const int h  = hn & 3;
  const int n  = hn >> 2;
  const int w  = threadIdx.x >> 6;    // 0..7
  const int l  = threadIdx.x & 63;
  const int lg = l >> 4;
  const int lm = l & 15;

  const unsigned short* xn = xinT + n * (512 * 64);
  const f32x4 zero4 = {0.f, 0.f, 0.f, 0.f};
  const float SC = 0.18033688011112042f;   // (1/sqrt(64)) * log2(e)
  const short8 ones = mk8(0x3F803F80u, 0x3F803F80u, 0x3F803F80u, 0x3F803F80u);

  const int qbA = w * 16;           // low half  (0..112)
  const int qbC = (8 + w) * 16;     // low half  (128..240)
  const int qbD = (23 - w) * 16;    // high half (256..368)
  const int qbB = (31 - w) * 16;    // high half (384..496)

  const float* bq = wq + h * 64 * 64;
  const float* bk = wk + h * 64 * 64;
  const float* bv = wv + h * 64 * 64;

  // ---- phase 0: stage K/V rows [0,256) ----
  stage_half(xn, 0, w, lg, lm, l, bk, bv, sK, sVf);
  __syncthreads();

  // A and C: Q-proj just-in-time, complete entirely in phase 0
  {
    short8 qB[2];
    qprojT(xn, bq, SC, qbA, lg, lm, qB);
    f32x4 o[4] = {zero4, zero4, zero4, zero4};
    f32x4 ls = zero4;
    run_chunk(sK, sVf, qB, o, ls, ones, qbA, 0, (qbA >> 5) << 5, 0, lg, lm, l);
    store_chunk(o, ls, heads, qbA, n, h, lg, lm);
  }
  {
    short8 qB[2];
    qprojT(xn, bq, SC, qbC, lg, lm, qB);
    f32x4 o[4] = {zero4, zero4, zero4, zero4};
    f32x4 ls = zero4;
    run_chunk(sK, sVf, qB, o, ls, ones, qbC, 0, (qbC >> 5) << 5, 0, lg, lm, l);
    store_chunk(o, ls, heads, qbC, n, h, lg, lm);
  }
  // D and B: phase-0 partial (slabs 0..224, no diagonal); carry only O-state
  f32x4 oD[4] = {zero4, zero4, zero4, zero4};
  f32x4 oB[4] = {zero4, zero4, zero4, zero4};
  f32x4 lsD = zero4, lsB = zero4;
  {
    short8 qB[2];
    qprojT(xn, bq, SC, qbD, lg, lm, qB);
    run_chunk(sK, sVf, qB, oD, lsD, ones, qbD, 0, 224, 0, lg, lm, l);
  }
  {
    short8 qB[2];
    qprojT(xn, bq, SC, qbB, lg, lm, qB);
    run_chunk(sK, sVf, qB, oB, lsB, ones, qbB, 0, 224, 0, lg, lm, l);
  }

  __syncthreads();   // all waves done with half 0

  // ---- phase 1: stage K/V rows [256,512) ----
  stage_half(xn, 1, w, lg, lm, l, bk, bv, sK, sVf);
  __syncthreads();

  {
    short8 qB[2];
    qprojT(xn, bq, SC, qbD, lg, lm, qB);   // deterministic re-projection
    run_chunk(sK, sVf, qB, oD, lsD, ones, qbD, 256, (qbD >> 5) << 5, 256, lg, lm, l);
    store_chunk(oD, lsD, heads, qbD, n, h, lg, lm);
  }
  {
    short8 qB[2];
    qprojT(xn, bq, SC, qbB, lg, lm, qB);
    run_chunk(sK, sVf, qB, oB, lsB, ones, qbB, 256, (qbB >> 5) << 5, 256, lg, lm, l);
    store_chunk(oB, lsB, heads, qbB, n, h, lg, lm);
  }
}

// ---------------- kernel 3: out = heads[65536,256] @ wo^T (r14-exact) ----------------
__global__ __launch_bounds__(256) void outproj_kernel(
    const unsigned short* __restrict__ heads,
    const float* __restrict__ wo,
    float* __restrict__ out) {
  const int w  = threadIdx.x >> 6;
  const int l  = threadIdx.x & 63;
  const int lg = l >> 4, lm = l & 15;
  const f32x4 zero4 = {0.f, 0.f, 0.f, 0.f};

  short8 woB[4][8];
#pragma unroll
  for (int nt = 0; nt < 4; ++nt)
#pragma unroll
    for (int ks = 0; ks < 8; ++ks)
      woB[nt][ks] = w8s(wo + (nt * 16 + lm) * 256 + ks * 32 + lg * 8, 1.0f);

  const int wid = blockIdx.x * 4 + w;
  for (int it = 0; it < 2; ++it) {
    int r0 = (wid * 2 + it) * 16;
    f32x4 acc[4];
#pragma unroll
    for (int nt = 0; nt < 4; ++nt) acc[nt] = zero4;
#pragma unroll
    for (int ks = 0; ks < 8; ++ks) {
      short8 aF = *(const short8*)&heads[(r0 + lm) * 256 + ks * 32 + lg * 8];
#pragma unroll
      for (int nt = 0; nt < 4; ++nt)
        acc[nt] = MFMA16(aF, woB[nt][ks], acc[nt]);
    }
#pragma unroll
    for (int nt = 0; nt < 4; ++nt)
#pragma unroll
      for (int r = 0; r < 4; ++r)
        out[(r0 + lg * 4 + r) * 64 + nt * 16 + lm] = acc[nt][r];
  }
}

// ---------------- launch (r14-exact ws layout) ----------------
extern "C" void kernel_launch(void* const* d_in, const int* in_sizes, int n_in,
                              void* d_out, int out_size, void* d_ws, size_t ws_size,
                              hipStream_t stream) {
  const float* x  = (const float*)d_in[0];
  const float* pe = (const float*)d_in[1];
  const float* wq = (const float*)d_in[2];
  const float* wk = (const float*)d_in[3];
  const float* wv = (const float*)d_in[4];
  const float* wo = (const float*)d_in[5];

  unsigned short* xinT  = (unsigned short*)d_ws;                          // 8 MiB  [n][t][d]
  unsigned short* heads = (unsigned short*)((char*)d_ws + (16u << 20));   // 32 MiB [t][n][256]

  prep_kernel<<<8192, 256, 0, stream>>>(x, pe, (unsigned*)xinT);
  attn_kernel<<<512, 512, 0, stream>>>(xinT, wq, wk, wv, heads);
  outproj_kernel<<<512, 256, 0, stream>>>(heads, wo, (float*)d_out);
}

// Round 16
// 107.305 us; speedup vs baseline: 1.2415x; 1.0401x over previous
//
#include <hip/hip_runtime.h>

// ---------------- types & helpers (NO inline asm) ----------------
using short8 = __attribute__((ext_vector_type(8))) short;   // 8 x bf16 (4 VGPRs)
using f32x4  = __attribute__((ext_vector_type(4))) float;
using u16x4  = __attribute__((ext_vector_type(4))) unsigned short;

#define MFMA16(A,B,C) __builtin_amdgcn_mfma_f32_16x16x32_bf16((A),(B),(C),0,0,0)

#if __has_builtin(__builtin_amdgcn_exp2f)
#define EXP2(x) __builtin_amdgcn_exp2f(x)
#else
#define EXP2(x) exp2f(x)
#endif

__device__ __forceinline__ unsigned short f2b(float f) {
  unsigned u = __float_as_uint(f);
  return (unsigned short)((u + 0x7fffu + ((u >> 16) & 1u)) >> 16);  // RNE
}
__device__ __forceinline__ short8 mk8(unsigned a, unsigned b, unsigned c, unsigned d) {
  union { unsigned u[4]; short8 s; } t; t.u[0]=a; t.u[1]=b; t.u[2]=c; t.u[3]=d; return t.s;
}
// trunc-pack two f32 -> bf16x2 (1 VALU op; r12-proven with self-consistent ls)
__device__ __forceinline__ unsigned pk2(float lo, float hi) {
  return __builtin_amdgcn_perm(__float_as_uint(hi), __float_as_uint(lo), 0x07060302u);
}
// 8 consecutive f32 -> bf16x8 fragment (optional scale, RNE)
__device__ __forceinline__ short8 w8s(const float* p, float s) {
  const f32x4* q = (const f32x4*)p;
  f32x4 a = q[0], b = q[1];
  short8 r;
  r[0]=(short)f2b(a[0]*s); r[1]=(short)f2b(a[1]*s); r[2]=(short)f2b(a[2]*s); r[3]=(short)f2b(a[3]*s);
  r[4]=(short)f2b(b[0]*s); r[5]=(short)f2b(b[1]*s); r[6]=(short)f2b(b[2]*s); r[7]=(short)f2b(b[3]*s);
  return r;
}

// T=512, N=128, D=64, H=4, HID=OUT=64

// ---------------- kernel 1: xin = x + pe, transpose to [n][t][d] bf16 (r15-exact) ----------------
__global__ void prep_kernel(const float* __restrict__ x, const float* __restrict__ pe,
                            unsigned* __restrict__ xinT) {
  int i2 = blockIdx.x * 256 + threadIdx.x;
  const float2* xp = (const float2*)x;
  const float2* pp = (const float2*)pe;
  float2 a = xp[i2], b = pp[i2];
  float s0 = a.x + b.x, s1 = a.y + b.y;
  int i = i2 << 1;
  int t = i >> 13, rem = i & 8191, n = rem >> 6, d = rem & 63;
  unsigned v = (unsigned)f2b(s0) | ((unsigned)f2b(s1) << 16);
  xinT[((n * 512 + t) * 64 + d) >> 1] = v;
}

// ---------------- attn building blocks ----------------
// LDS-free Q^T projection (r15-proven): qt = MFMA(wq-as-A, xin-as-B) -> lane
// (lg,lm) holds Q^T[e=nt*16+4lg+r][q=lm]; pack qB with kappa'(lg,i) =
// 32ks + 16*(i>>2) + 4lg + (i&3).
__device__ __forceinline__ void qprojT(
    const unsigned short* xn, const float* bq, float sc, int qb16,
    int lg, int lm, short8 (&qB)[2]) {
  const f32x4 zero4 = {0.f, 0.f, 0.f, 0.f};
  short8 aX0 = *(const short8*)(xn + (qb16 + lm) * 64 + lg * 8);
  short8 aX1 = *(const short8*)(xn + (qb16 + lm) * 64 + 32 + lg * 8);
  f32x4 qt[4];
#pragma unroll
  for (int nt = 0; nt < 4; ++nt) {   // per-nt wq fragments (caps pressure)
    const float* p = bq + (nt * 16 + lm) * 64 + lg * 8;
    short8 w0 = w8s(p, sc), w1 = w8s(p + 32, sc);
    f32x4 a = zero4;
    a = MFMA16(w0, aX0, a);
    a = MFMA16(w1, aX1, a);
    qt[nt] = a;
  }
#pragma unroll
  for (int ks = 0; ks < 2; ++ks) {
    short8 q;
#pragma unroll
    for (int i = 0; i < 8; ++i) q[i] = (short)f2b(qt[2 * ks + (i >> 2)][i & 3]);
    qB[ks] = q;
  }
}

// stage K + V for phase half p. K stored under pi(e) = 32*(nt>>1) + 8*(lm>>2)
// + 4*(nt&1) + (lm&3) so the kappa' fragment is 16B-contiguous: the aK read
// is then r12's conflict-free single ds_read_b128 pattern. Scatter write has
// the same 8-banks/2-lanes-per-dword structure that measured 0 conflicts (r12).
__device__ __forceinline__ void stage_half(
    const unsigned short* xn, int p, int w, int lg, int lm, int l,
    const float* bk, const float* bv, unsigned short* sK, short8* sVf) {
  const f32x4 zero4 = {0.f, 0.f, 0.f, 0.f};
  int s0g = p * 256 + w * 32;
  int sl0 = w * 32;
  short8 aX[2][2];
#pragma unroll
  for (int km = 0; km < 2; ++km) {
    aX[km][0] = *(const short8*)(xn + (s0g + km * 16 + lm) * 64 + lg * 8);
    aX[km][1] = *(const short8*)(xn + (s0g + km * 16 + lm) * 64 + 32 + lg * 8);
  }
#pragma unroll
  for (int nt = 0; nt < 4; ++nt) {
    const float* bko = bk + (nt * 16 + lm) * 64 + lg * 8;
    const float* bvo = bv + (nt * 16 + lm) * 64 + lg * 8;
    short8 wk0 = w8s(bko, 1.0f), wk1 = w8s(bko + 32, 1.0f);
    short8 wv0 = w8s(bvo, 1.0f), wv1 = w8s(bvo + 32, 1.0f);
    f32x4 k0 = zero4, k1 = zero4, v0 = zero4, v1 = zero4;
    k0 = MFMA16(aX[0][0], wk0, k0); k0 = MFMA16(aX[0][1], wk1, k0);
    k1 = MFMA16(aX[1][0], wk0, k1); k1 = MFMA16(aX[1][1], wk1, k1);
    v0 = MFMA16(aX[0][0], wv0, v0); v0 = MFMA16(aX[0][1], wv1, v0);
    v1 = MFMA16(aX[1][0], wv0, v1); v1 = MFMA16(aX[1][1], wv1, v1);
    // K scatter under pi-layout (value for e=nt*16+lm goes to pos)
    int pos = ((nt & 2) << 4) + ((lm >> 2) << 3) + ((nt & 1) << 2) + (lm & 3);
#pragma unroll
    for (int r = 0; r < 4; ++r) {
      int row0 = sl0 + lg * 4 + r;
      int row1 = sl0 + 16 + lg * 4 + r;
      sK[row0 * 64 + (pos ^ ((row0 & 7) << 3))] = f2b(k0[r]);
      sK[row1 * 64 + (pos ^ ((row1 & 7) << 3))] = f2b(k1[r]);
    }
    short8 vv;
    vv[0]=(short)f2b(v0[0]); vv[1]=(short)f2b(v0[1]);
    vv[2]=(short)f2b(v0[2]); vv[3]=(short)f2b(v0[3]);
    vv[4]=(short)f2b(v1[0]); vv[5]=(short)f2b(v1[1]);
    vv[6]=(short)f2b(v1[2]); vv[7]=(short)f2b(v1[3]);
    sVf[(w * 4 + nt) * 64 + l] = vv;
  }
}

// slabs [kb_lo, kb_hi] for a 16-row chunk at qb16. aK: ONE ds_read_b128 per
// ks (r12's conflict-free address line); pi-layout delivers kappa' order,
// matching qB. O^T accumulation (r14-proven): lane -> O[q=lm][o=ot*16+4lg+r].
__device__ __forceinline__ void run_chunk(
    const unsigned short* sK, const short8* sVf, const short8 (&qB)[2],
    f32x4 (&oAcc)[4], f32x4& lsAcc, const short8 ones,
    int qb16, int kb_lo, int kb_hi, int pbase, int lg, int lm, int l) {
  const f32x4 zero4 = {0.f, 0.f, 0.f, 0.f};
  for (int kb = kb_lo; kb <= kb_hi; kb += 32) {
    int kl = kb - pbase;
    short8 vB[4];
#pragma unroll
    for (int ot = 0; ot < 4; ++ot) vB[ot] = sVf[(((kl >> 5) * 4) + ot) * 64 + l];
    f32x4 st[2];
#pragma unroll
    for (int km = 0; km < 2; ++km) {   // per-km aK (8 regs live)
      int row = kl + km * 16 + lm;
      int rb = row * 64, xorv = (row & 7) << 3;
      short8 aK0 = *(const short8*)&sK[rb + ((lg * 8) ^ xorv)];
      short8 aK1 = *(const short8*)&sK[rb + ((32 + lg * 8) ^ xorv)];
      f32x4 a = zero4;
      a = MFMA16(aK0, qB[0], a);
      a = MFMA16(aK1, qB[1], a);
      st[km] = a;
    }
    if (kb + 32 > qb16) {               // diagonal-crossing slab
      int qrl = qb16 - kb + lm;
#pragma unroll
      for (int km = 0; km < 2; ++km)
#pragma unroll
        for (int r = 0; r < 4; ++r)
          if (km * 16 + lg * 4 + r > qrl) st[km][r] = -1e30f;
    }
#pragma unroll
    for (int km = 0; km < 2; ++km)
#pragma unroll
      for (int r = 0; r < 4; ++r) st[km][r] = EXP2(st[km][r]);
    short8 pA = mk8(pk2(st[0][0], st[0][1]), pk2(st[0][2], st[0][3]),
                    pk2(st[1][0], st[1][1]), pk2(st[1][2], st[1][3]));
    lsAcc = MFMA16(ones, pA, lsAcc);    // O^T form: ls[q=lm] in every reg
#pragma unroll
    for (int ot = 0; ot < 4; ++ot) oAcc[ot] = MFMA16(vB[ot], pA, oAcc[ot]);
  }
}

// normalize + DIRECT global store (r14-proven): lane (lg,lm) owns row t=qb16+lm
__device__ __forceinline__ void store_chunk(
    const f32x4 (&oAcc)[4], const f32x4& lsAcc, unsigned short* heads,
    int qb16, int n, int h, int lg, int lm) {
  float li = 1.0f / lsAcc[0];
  unsigned short* base = heads + ((qb16 + lm) * 128 + n) * 256 + h * 64 + lg * 4;
#pragma unroll
  for (int ot = 0; ot < 4; ++ot) {
    u16x4 v;
#pragma unroll
    for (int r = 0; r < 4; ++r) v[r] = f2b(oAcc[ot][r] * li);
    *(u16x4*)(base + ot * 16) = v;
  }
}

// ---------------- kernel 2: fused QKV + causal flash attention ----------------
// r15 structure (512 thr / 8 waves, 65536 B LDS, 16-row chunks {w,8+w,23-w,31-w},
// JIT qprojT, O^T direct store) + pi-relayout of sK -> aK is a single
// conflict-free ds_read_b128 (fixes r15's 4.45M bank conflicts).
__global__ __launch_bounds__(512) void attn_kernel(
    const unsigned short* __restrict__ xinT,
    const float* __restrict__ wq, const float* __restrict__ wk,
    const float* __restrict__ wv, unsigned short* __restrict__ heads) {
  __shared__ unsigned short sK[256 * 64];   // 32 KiB, pi-layout + XOR swizzle
  __shared__ short8 sVf[8 * 4 * 64];        // 32 KiB kappa2 V fragments

  const int hn = blockIdx.x;
  const int h  = hn & 3;
  const int n  = hn >> 2;
  const int w  = threadIdx.x >> 6;    // 0..7
  const int l  = threadIdx.x & 63;
  const int lg = l >> 4;
  const int lm = l & 15;

  const unsigned short* xn = xinT + n * (512 * 64);
  const f32x4 zero4 = {0.f, 0.f, 0.f, 0.f};
  const float SC = 0.18033688011112042f;   // (1/sqrt(64)) * log2(e)
  const short8 ones = mk8(0x3F803F80u, 0x3F803F80u, 0x3F803F80u, 0x3F803F80u);

  const int qbA = w * 16;           // low half  (0..112)
  const int qbC = (8 + w) * 16;     // low half  (128..240)
  const int qbD = (23 - w) * 16;    // high half (256..368)
  const int qbB = (31 - w) * 16;    // high half (384..496)

  const float* bq = wq + h * 64 * 64;
  const float* bk = wk + h * 64 * 64;
  const float* bv = wv + h * 64 * 64;

  // ---- phase 0: stage K/V rows [0,256) ----
  stage_half(xn, 0, w, lg, lm, l, bk, bv, sK, sVf);
  __syncthreads();

  // A and C: Q-proj just-in-time, complete entirely in phase 0
  {
    short8 qB[2];
    qprojT(xn, bq, SC, qbA, lg, lm, qB);
    f32x4 o[4] = {zero4, zero4, zero4, zero4};
    f32x4 ls = zero4;
    run_chunk(sK, sVf, qB, o, ls, ones, qbA, 0, (qbA >> 5) << 5, 0, lg, lm, l);
    store_chunk(o, ls, heads, qbA, n, h, lg, lm);
  }
  {
    short8 qB[2];
    qprojT(xn, bq, SC, qbC, lg, lm, qB);
    f32x4 o[4] = {zero4, zero4, zero4, zero4};
    f32x4 ls = zero4;
    run_chunk(sK, sVf, qB, o, ls, ones, qbC, 0, (qbC >> 5) << 5, 0, lg, lm, l);
    store_chunk(o, ls, heads, qbC, n, h, lg, lm);
  }
  // D and B: phase-0 partial (slabs 0..224, no diagonal); carry only O-state
  f32x4 oD[4] = {zero4, zero4, zero4, zero4};
  f32x4 oB[4] = {zero4, zero4, zero4, zero4};
  f32x4 lsD = zero4, lsB = zero4;
  {
    short8 qB[2];
    qprojT(xn, bq, SC, qbD, lg, lm, qB);
    run_chunk(sK, sVf, qB, oD, lsD, ones, qbD, 0, 224, 0, lg, lm, l);
  }
  {
    short8 qB[2];
    qprojT(xn, bq, SC, qbB, lg, lm, qB);
    run_chunk(sK, sVf, qB, oB, lsB, ones, qbB, 0, 224, 0, lg, lm, l);
  }

  __syncthreads();   // all waves done with half 0

  // ---- phase 1: stage K/V rows [256,512) ----
  stage_half(xn, 1, w, lg, lm, l, bk, bv, sK, sVf);
  __syncthreads();

  {
    short8 qB[2];
    qprojT(xn, bq, SC, qbD, lg, lm, qB);   // deterministic re-projection
    run_chunk(sK, sVf, qB, oD, lsD, ones, qbD, 256, (qbD >> 5) << 5, 256, lg, lm, l);
    store_chunk(oD, lsD, heads, qbD, n, h, lg, lm);
  }
  {
    short8 qB[2];
    qprojT(xn, bq, SC, qbB, lg, lm, qB);
    run_chunk(sK, sVf, qB, oB, lsB, ones, qbB, 256, (qbB >> 5) << 5, 256, lg, lm, l);
    store_chunk(oB, lsB, heads, qbB, n, h, lg, lm);
  }
}

// ---------------- kernel 3: out = heads[65536,256] @ wo^T (r15-exact) ----------------
__global__ __launch_bounds__(256) void outproj_kernel(
    const unsigned short* __restrict__ heads,
    const float* __restrict__ wo,
    float* __restrict__ out) {
  const int w  = threadIdx.x >> 6;
  const int l  = threadIdx.x & 63;
  const int lg = l >> 4, lm = l & 15;
  const f32x4 zero4 = {0.f, 0.f, 0.f, 0.f};

  short8 woB[4][8];
#pragma unroll
  for (int nt = 0; nt < 4; ++nt)
#pragma unroll
    for (int ks = 0; ks < 8; ++ks)
      woB[nt][ks] = w8s(wo + (nt * 16 + lm) * 256 + ks * 32 + lg * 8, 1.0f);

  const int wid = blockIdx.x * 4 + w;
  for (int it = 0; it < 2; ++it) {
    int r0 = (wid * 2 + it) * 16;
    f32x4 acc[4];
#pragma unroll
    for (int nt = 0; nt < 4; ++nt) acc[nt] = zero4;
#pragma unroll
    for (int ks = 0; ks < 8; ++ks) {
      short8 aF = *(const short8*)&heads[(r0 + lm) * 256 + ks * 32 + lg * 8];
#pragma unroll
      for (int nt = 0; nt < 4; ++nt)
        acc[nt] = MFMA16(aF, woB[nt][ks], acc[nt]);
    }
#pragma unroll
    for (int nt = 0; nt < 4; ++nt)
#pragma unroll
      for (int r = 0; r < 4; ++r)
        out[(r0 + lg * 4 + r) * 64 + nt * 16 + lm] = acc[nt][r];
  }
}

// ---------------- launch (r15-exact ws layout) ----------------
extern "C" void kernel_launch(void* const* d_in, const int* in_sizes, int n_in,
                              void* d_out, int out_size, void* d_ws, size_t ws_size,
                              hipStream_t stream) {
  const float* x  = (const float*)d_in[0];
  const float* pe = (const float*)d_in[1];
  const float* wq = (const float*)d_in[2];
  const float* wk = (const float*)d_in[3];
  const float* wv = (const float*)d_in[4];
  const float* wo = (const float*)d_in[5];

  unsigned short* xinT  = (unsigned short*)d_ws;                          // 8 MiB  [n][t][d]
  unsigned short* heads = (unsigned short*)((char*)d_ws + (16u << 20));   // 32 MiB [t][n][256]

  prep_kernel<<<8192, 256, 0, stream>>>(x, pe, (unsigned*)xinT);
  attn_kernel<<<512, 512, 0, stream>>>(xinT, wq, wk, wv, heads);
  outproj_kernel<<<512, 256, 0, stream>>>(heads, wo, (float*)d_out);
}

// Round 17
// 86.292 us; speedup vs baseline: 1.5438x; 1.2435x over previous
//
#include <hip/hip_runtime.h>

// ---------------- types & helpers (NO inline asm) ----------------
using short8 = __attribute__((ext_vector_type(8))) short;   // 8 x bf16 (4 VGPRs)
using f32x4  = __attribute__((ext_vector_type(4))) float;
using u16x4  = __attribute__((ext_vector_type(4))) unsigned short;

#define MFMA16(A,B,C) __builtin_amdgcn_mfma_f32_16x16x32_bf16((A),(B),(C),0,0,0)

#if __has_builtin(__builtin_amdgcn_exp2f)
#define EXP2(x) __builtin_amdgcn_exp2f(x)
#else
#define EXP2(x) exp2f(x)
#endif

__device__ __forceinline__ unsigned short f2b(float f) {
  unsigned u = __float_as_uint(f);
  return (unsigned short)((u + 0x7fffu + ((u >> 16) & 1u)) >> 16);  // RNE
}
__device__ __forceinline__ short8 mk8(unsigned a, unsigned b, unsigned c, unsigned d) {
  union { unsigned u[4]; short8 s; } t; t.u[0]=a; t.u[1]=b; t.u[2]=c; t.u[3]=d; return t.s;
}
// trunc-pack two f32 -> bf16x2 (1 VALU op; r12-proven with self-consistent ls)
__device__ __forceinline__ unsigned pk2(float lo, float hi) {
  return __builtin_amdgcn_perm(__float_as_uint(hi), __float_as_uint(lo), 0x07060302u);
}
// 8 consecutive f32 -> bf16x8 fragment (optional scale, RNE)
__device__ __forceinline__ short8 w8s(const float* p, float s) {
  const f32x4* q = (const f32x4*)p;
  f32x4 a = q[0], b = q[1];
  short8 r;
  r[0]=(short)f2b(a[0]*s); r[1]=(short)f2b(a[1]*s); r[2]=(short)f2b(a[2]*s); r[3]=(short)f2b(a[3]*s);
  r[4]=(short)f2b(b[0]*s); r[5]=(short)f2b(b[1]*s); r[6]=(short)f2b(b[2]*s); r[7]=(short)f2b(b[3]*s);
  return r;
}

// T=512, N=128, D=64, H=4, HID=OUT=64

// ---------------- kernel 1: xin = x + pe, transpose to [n][t][d] bf16 (r16-exact) ----------------
__global__ void prep_kernel(const float* __restrict__ x, const float* __restrict__ pe,
                            unsigned* __restrict__ xinT) {
  int i2 = blockIdx.x * 256 + threadIdx.x;
  const float2* xp = (const float2*)x;
  const float2* pp = (const float2*)pe;
  float2 a = xp[i2], b = pp[i2];
  float s0 = a.x + b.x, s1 = a.y + b.y;
  int i = i2 << 1;
  int t = i >> 13, rem = i & 8191, n = rem >> 6, d = rem & 63;
  unsigned v = (unsigned)f2b(s0) | ((unsigned)f2b(s1) << 16);
  xinT[((n * 512 + t) * 64 + d) >> 1] = v;
}

// ---------------- attn building blocks ----------------
// LDS-free Q^T projection (r15-proven): qt = MFMA(wq-as-A, xin-as-B) -> lane
// (lg,lm) holds Q^T[e=nt*16+4lg+r][q=lm]; pack qB with kappa'(lg,i) =
// 32ks + 16*(i>>2) + 4lg + (i&3).
__device__ __forceinline__ void qprojT(
    const unsigned short* xn, const float* bq, float sc, int qb16,
    int lg, int lm, short8 (&qB)[2]) {
  const f32x4 zero4 = {0.f, 0.f, 0.f, 0.f};
  short8 aX0 = *(const short8*)(xn + (qb16 + lm) * 64 + lg * 8);
  short8 aX1 = *(const short8*)(xn + (qb16 + lm) * 64 + 32 + lg * 8);
  f32x4 qt[4];
#pragma unroll
  for (int nt = 0; nt < 4; ++nt) {   // per-nt wq fragments (caps pressure)
    const float* p = bq + (nt * 16 + lm) * 64 + lg * 8;
    short8 w0 = w8s(p, sc), w1 = w8s(p + 32, sc);
    f32x4 a = zero4;
    a = MFMA16(w0, aX0, a);
    a = MFMA16(w1, aX1, a);
    qt[nt] = a;
  }
#pragma unroll
  for (int ks = 0; ks < 2; ++ks) {
    short8 q;
#pragma unroll
    for (int i = 0; i < 8; ++i) q[i] = (short)f2b(qt[2 * ks + (i >> 2)][i & 3]);
    qB[ks] = q;
  }
}

// stage one 32-row slab of K + V. K stored under pi(e) = 32*(nt>>1) +
// 8*(lm>>2) + 4*(nt&1) + (lm&3) (+XOR row swizzle) so the kappa' fragment is
// one conflict-free ds_read_b128 (r16-proven). V as kappa2 lane-linear short8.
__device__ __forceinline__ void stage_slab(
    const unsigned short* xn, int slab, int lg, int lm, int l,
    const float* bk, const float* bv, unsigned short* sK, short8* sVf) {
  const f32x4 zero4 = {0.f, 0.f, 0.f, 0.f};
  int s0 = slab * 32;
  short8 aX[2][2];
#pragma unroll
  for (int km = 0; km < 2; ++km) {
    aX[km][0] = *(const short8*)(xn + (s0 + km * 16 + lm) * 64 + lg * 8);
    aX[km][1] = *(const short8*)(xn + (s0 + km * 16 + lm) * 64 + 32 + lg * 8);
  }
#pragma unroll
  for (int nt = 0; nt < 4; ++nt) {
    const float* bko = bk + (nt * 16 + lm) * 64 + lg * 8;
    const float* bvo = bv + (nt * 16 + lm) * 64 + lg * 8;
    short8 wk0 = w8s(bko, 1.0f), wk1 = w8s(bko + 32, 1.0f);
    short8 wv0 = w8s(bvo, 1.0f), wv1 = w8s(bvo + 32, 1.0f);
    f32x4 k0 = zero4, k1 = zero4, v0 = zero4, v1 = zero4;
    k0 = MFMA16(aX[0][0], wk0, k0); k0 = MFMA16(aX[0][1], wk1, k0);
    k1 = MFMA16(aX[1][0], wk0, k1); k1 = MFMA16(aX[1][1], wk1, k1);
    v0 = MFMA16(aX[0][0], wv0, v0); v0 = MFMA16(aX[0][1], wv1, v0);
    v1 = MFMA16(aX[1][0], wv0, v1); v1 = MFMA16(aX[1][1], wv1, v1);
    int pos = ((nt & 2) << 4) + ((lm >> 2) << 3) + ((nt & 1) << 2) + (lm & 3);
#pragma unroll
    for (int r = 0; r < 4; ++r) {
      int row0 = s0 + lg * 4 + r;
      int row1 = s0 + 16 + lg * 4 + r;
      sK[row0 * 64 + (pos ^ ((row0 & 7) << 3))] = f2b(k0[r]);
      sK[row1 * 64 + (pos ^ ((row1 & 7) << 3))] = f2b(k1[r]);
    }
    short8 vv;
    vv[0]=(short)f2b(v0[0]); vv[1]=(short)f2b(v0[1]);
    vv[2]=(short)f2b(v0[2]); vv[3]=(short)f2b(v0[3]);
    vv[4]=(short)f2b(v1[0]); vv[5]=(short)f2b(v1[1]);
    vv[6]=(short)f2b(v1[2]); vv[7]=(short)f2b(v1[3]);
    sVf[(slab * 4 + nt) * 64 + l] = vv;
  }
}

// ---------------- kernel 2: fused QKV + causal flash attention ----------------
// 512 thr / 8 waves, LDS = 64K sK + 64K sVf = 131072 B (proven envelope).
// Full K/V staged ONCE (r12's 136 slab-step shape); 32-row chunks {w, 15-w}
// = 17 slab-steps/wave. qprojT JIT (no LDS, no pre-barrier); pi-layout
// conflict-free aK; O^T PV with lane-local ls and direct global stores.
// ONE __syncthreads in the whole kernel.
__global__ __launch_bounds__(512) void attn_kernel(
    const unsigned short* __restrict__ xinT,
    const float* __restrict__ wq, const float* __restrict__ wk,
    const float* __restrict__ wv, unsigned short* __restrict__ heads) {
  __shared__ unsigned short sK[512 * 64];   // 64 KiB, pi-layout + XOR swizzle
  __shared__ short8 sVf[16 * 4 * 64];       // 64 KiB kappa2 V fragments

  const int hn = blockIdx.x;
  const int h  = hn & 3;
  const int n  = hn >> 2;
  const int w  = threadIdx.x >> 6;    // 0..7
  const int l  = threadIdx.x & 63;
  const int lg = l >> 4;
  const int lm = l & 15;

  const unsigned short* xn = xinT + n * (512 * 64);
  const f32x4 zero4 = {0.f, 0.f, 0.f, 0.f};
  const float SC = 0.18033688011112042f;   // (1/sqrt(64)) * log2(e)
  const short8 ones = mk8(0x3F803F80u, 0x3F803F80u, 0x3F803F80u, 0x3F803F80u);

  const float* bq = wq + h * 64 * 64;
  const float* bk = wk + h * 64 * 64;
  const float* bv = wv + h * 64 * 64;

  // ---- stage all 512 K/V rows (wave w: slabs {2w, 2w+1}) ----
  stage_slab(xn, w * 2,     lg, lm, l, bk, bv, sK, sVf);
  stage_slab(xn, w * 2 + 1, lg, lm, l, bk, bv, sK, sVf);
  __syncthreads();   // the kernel's only barrier

  // ---- chunks {w, 15-w}: 32 rows each, 17 slab-steps/wave total ----
  for (int c = 0; c < 2; ++c) {
    const int chunk = c ? (15 - w) : w;
    const int qb = chunk * 32;

    // JIT Q^T projection for both 16-row halves (LDS-free, r15-proven)
    short8 qB[2][2];   // [qn][ks]
    qprojT(xn, bq, SC, qb,      lg, lm, qB[0]);
    qprojT(xn, bq, SC, qb + 16, lg, lm, qB[1]);

    f32x4 oAcc[2][4];
#pragma unroll
    for (int mo = 0; mo < 2; ++mo)
#pragma unroll
      for (int ot = 0; ot < 4; ++ot) oAcc[mo][ot] = zero4;
    f32x4 lsAcc[2] = {zero4, zero4};

    for (int kb = 0; kb <= qb; kb += 32) {
      short8 vB[4];
#pragma unroll
      for (int ot = 0; ot < 4; ++ot) vB[ot] = sVf[(((kb >> 5) * 4) + ot) * 64 + l];
      // S^T: per-km aK (transient 8 regs), one conflict-free b128 per half
      f32x4 st[2][2];
#pragma unroll
      for (int km = 0; km < 2; ++km) {
        int row = kb + km * 16 + lm;
        int rb = row * 64, xorv = (row & 7) << 3;
        short8 aK0 = *(const short8*)&sK[rb + ((lg * 8) ^ xorv)];
        short8 aK1 = *(const short8*)&sK[rb + ((32 + lg * 8) ^ xorv)];
#pragma unroll
        for (int qn = 0; qn < 2; ++qn) {
          f32x4 a = zero4;
          a = MFMA16(aK0, qB[qn][0], a);
          a = MFMA16(aK1, qB[qn][1], a);
          st[km][qn] = a;
        }
      }
      if (kb == qb) {   // diagonal slab: causal mask -> exp2(-1e30) = 0
#pragma unroll
        for (int km = 0; km < 2; ++km)
#pragma unroll
          for (int qn = 0; qn < 2; ++qn) {
            if (km == 0 && qn == 1) continue;   // never masked
#pragma unroll
            for (int r = 0; r < 4; ++r) {
              int key = km * 16 + lg * 4 + r, qr = qn * 16 + lm;
              if (key > qr) st[km][qn][r] = -1e30f;
            }
          }
      }
#pragma unroll
      for (int km = 0; km < 2; ++km)
#pragma unroll
        for (int qn = 0; qn < 2; ++qn)
#pragma unroll
          for (int r = 0; r < 4; ++r) st[km][qn][r] = EXP2(st[km][qn][r]);
      // per-mo pack + O^T accumulate (r14-proven operand order)
#pragma unroll
      for (int mo = 0; mo < 2; ++mo) {
        short8 pA = mk8(pk2(st[0][mo][0], st[0][mo][1]), pk2(st[0][mo][2], st[0][mo][3]),
                        pk2(st[1][mo][0], st[1][mo][1]), pk2(st[1][mo][2], st[1][mo][3]));
        lsAcc[mo] = MFMA16(ones, pA, lsAcc[mo]);   // ls[q=lm] in every reg
#pragma unroll
        for (int ot = 0; ot < 4; ++ot) oAcc[mo][ot] = MFMA16(vB[ot], pA, oAcc[mo][ot]);
      }
    }

    // ---- direct store: lane (lg,lm) owns t=qb+mo*16+lm, o=ot*16+4lg+r ----
#pragma unroll
    for (int mo = 0; mo < 2; ++mo) {
      float li = 1.0f / lsAcc[mo][0];
      unsigned short* base = heads + ((qb + mo * 16 + lm) * 128 + n) * 256 + h * 64 + lg * 4;
#pragma unroll
      for (int ot = 0; ot < 4; ++ot) {
        u16x4 v;
#pragma unroll
        for (int r = 0; r < 4; ++r) v[r] = f2b(oAcc[mo][ot][r] * li);
        *(u16x4*)(base + ot * 16) = v;
      }
    }
  }
}

// ---------------- kernel 3: out = heads[65536,256] @ wo^T (r16-exact) ----------------
__global__ __launch_bounds__(256) void outproj_kernel(
    const unsigned short* __restrict__ heads,
    const float* __restrict__ wo,
    float* __restrict__ out) {
  const int w  = threadIdx.x >> 6;
  const int l  = threadIdx.x & 63;
  const int lg = l >> 4, lm = l & 15;
  const f32x4 zero4 = {0.f, 0.f, 0.f, 0.f};

  short8 woB[4][8];
#pragma unroll
  for (int nt = 0; nt < 4; ++nt)
#pragma unroll
    for (int ks = 0; ks < 8; ++ks)
      woB[nt][ks] = w8s(wo + (nt * 16 + lm) * 256 + ks * 32 + lg * 8, 1.0f);

  const int wid = blockIdx.x * 4 + w;
  for (int it = 0; it < 2; ++it) {
    int r0 = (wid * 2 + it) * 16;
    f32x4 acc[4];
#pragma unroll
    for (int nt = 0; nt < 4; ++nt) acc[nt] = zero4;
#pragma unroll
    for (int ks = 0; ks < 8; ++ks) {
      short8 aF = *(const short8*)&heads[(r0 + lm) * 256 + ks * 32 + lg * 8];
#pragma unroll
      for (int nt = 0; nt < 4; ++nt)
        acc[nt] = MFMA16(aF, woB[nt][ks], acc[nt]);
    }
#pragma unroll
    for (int nt = 0; nt < 4; ++nt)
#pragma unroll
      for (int r = 0; r < 4; ++r)
        out[(r0 + lg * 4 + r) * 64 + nt * 16 + lm] = acc[nt][r];
  }
}

// ---------------- launch (r16-exact ws layout) ----------------
extern "C" void kernel_launch(void* const* d_in, const int* in_sizes, int n_in,
                              void* d_out, int out_size, void* d_ws, size_t ws_size,
                              hipStream_t stream) {
  const float* x  = (const float*)d_in[0];
  const float* pe = (const float*)d_in[1];
  const float* wq = (const float*)d_in[2];
  const float* wk = (const float*)d_in[3];
  const float* wv = (const float*)d_in[4];
  const float* wo = (const float*)d_in[5];

  unsigned short* xinT  = (unsigned short*)d_ws;                          // 8 MiB  [n][t][d]
  unsigned short* heads = (unsigned short*)((char*)d_ws + (16u << 20));   // 32 MiB [t][n][256]

  prep_kernel<<<8192, 256, 0, stream>>>(x, pe, (unsigned*)xinT);
  attn_kernel<<<512, 512, 0, stream>>>(xinT, wq, wk, wv, heads);
  outproj_kernel<<<512, 256, 0, stream>>>(heads, wo, (float*)d_out);
}